// Round 1
// baseline (353.589 us; speedup 1.0000x reference)
//
#include <hip/hip_runtime.h>

// Problem constants (from setup_inputs): x[B=32, N=8192, F=256] fp32, k=1024.
#define B_DIM 32
#define N_DIM 8192
#define F_DIM 256
#define K_DIM 1024

#define NBITS 13                    // histogram on top 13 bits of ord (sign+exp+4 mant)
#define NBINS (1 << NBITS)          // 8192 bins, 32 KB LDS
#define BPT   (NBINS / 1024)        // bins per thread in scan = 8
#define KPT   (N_DIM / 1024)        // keys per thread = 8
#define TCAP  1024                  // threshold-bin tie list capacity (expected ~100)

// Monotonic float32 -> uint32 transform (total order; inputs are normals, no NaN).
__device__ __forceinline__ unsigned int f32_ord(float v) {
    unsigned int u = __float_as_uint(v);
    return (u & 0x80000000u) ? ~u : (u | 0x80000000u);
}

// ---------------------------------------------------------------------------
// One block per batch, 1024 threads.
// 1. Load 8192 keys (u64 = ord<<32 | (N-1-row); distinct, desc == top_k order)
//    into registers (8/thread).
// 2. 13-bit LDS histogram -> suffix scan -> exact threshold bin T and count
//    C1 of elements strictly above bin T.
// 3. Compact: bin>T -> SEL (unordered), bin==T -> tie list L.
// 4. Rank L on full u64 keys; ranks < (1024-C1) fill SEL[C1..1023]. Exact.
// 5. One 1024-element bitonic sort (desc) of SEL, write indices.
// Replaces: 8x 1024-sorts (55 passes x 256 blocks) + 34-pass merge + 4 MB of
// global runs traffic.
// ---------------------------------------------------------------------------
__global__ __launch_bounds__(1024)
void select_sort_kernel(const float* __restrict__ x, int* __restrict__ idx_out) {
    __shared__ unsigned int       HIST[NBINS];   // 32 KB
    __shared__ unsigned int       P[1024];       // 4 KB suffix-scan partials
    __shared__ unsigned long long SEL[K_DIM];    // 8 KB selected keys
    __shared__ unsigned long long L[TCAP];       // 8 KB threshold-bin ties
    __shared__ unsigned int       sc[4];         // cntHi, cntT, T, C1

    const int b = blockIdx.x;
    const int t = threadIdx.x;
    const float* xcol = x + (size_t)b * N_DIM * F_DIM + (F_DIM - 1);

    #pragma unroll
    for (int i = 0; i < BPT; ++i) HIST[t + i * 1024] = 0;
    if (t < 4) sc[t] = 0;

    // Keys live in registers: 8 u64 per thread.
    unsigned long long key[KPT];
    #pragma unroll
    for (int i = 0; i < KPT; ++i) {
        int row = t + i * 1024;
        float v = xcol[(size_t)row * F_DIM];
        key[i] = ((unsigned long long)f32_ord(v) << 32) |
                 (unsigned int)(N_DIM - 1 - row);
    }
    __syncthreads();

    // Histogram on top NBITS bits.
    #pragma unroll
    for (int i = 0; i < KPT; ++i)
        atomicAdd(&HIST[(unsigned int)(key[i] >> (64 - NBITS))], 1u);
    __syncthreads();

    // Per-thread partial over 8 bins, then Hillis-Steele suffix scan (10 passes).
    {
        unsigned int s = 0;
        #pragma unroll
        for (int i = 0; i < BPT; ++i) s += HIST[t * BPT + i];
        P[t] = s;
        __syncthreads();
        for (int off = 1; off < 1024; off <<= 1) {
            unsigned int v = P[t] + ((t + off < 1024) ? P[t + off] : 0u);
            __syncthreads();
            P[t] = v;
            __syncthreads();
        }
    }

    // P is non-increasing; unique boundary g = largest group with suffix >= K.
    if (P[t] >= K_DIM && (t == 1023 || P[t + 1] < K_DIM)) sc[2] = (unsigned int)t;
    __syncthreads();
    if (t == 0) {
        unsigned int g   = sc[2];
        unsigned int run = (g == 1023) ? 0u : P[g + 1];   // count above group g
        unsigned int T = 0, C1 = 0;
        for (int bin = (int)g * BPT + BPT - 1; bin >= (int)g * BPT; --bin) {
            unsigned int c = HIST[bin];
            if (run + c >= K_DIM) { T = (unsigned int)bin; C1 = run; break; }
            run += c;
        }
        sc[2] = T; sc[3] = C1;       // C1 < K by construction, C1 + HIST[T] >= K
    }
    __syncthreads();

    const unsigned int T  = sc[2];
    const unsigned int C1 = sc[3];
    const unsigned int R  = K_DIM - C1;   // needed from threshold bin, 1..HIST[T]

    // Compact from registers.
    #pragma unroll
    for (int i = 0; i < KPT; ++i) {
        unsigned int bin = (unsigned int)(key[i] >> (64 - NBITS));
        if (bin > T) {
            SEL[atomicAdd(&sc[0], 1u)] = key[i];
        } else if (bin == T) {
            unsigned int pos = atomicAdd(&sc[1], 1u);
            if (pos < TCAP) L[pos] = key[i];
        }
    }
    __syncthreads();

    // Rank threshold-bin ties on full u64 (distinct -> exact bijection of ranks).
    const unsigned int nT = min(sc[1], (unsigned int)TCAP);
    for (unsigned int i = t; i < nT; i += 1024) {
        unsigned long long kv = L[i];
        unsigned int rank = 0;
        for (unsigned int j = 0; j < nT; ++j) rank += (L[j] > kv) ? 1u : 0u;
        if (rank < R) SEL[C1 + rank] = kv;
    }
    __syncthreads();

    // Bitonic sort SEL[1024] descending: 55 passes, 512 pairs (t < 512 active).
    for (unsigned int kk = 2; kk <= K_DIM; kk <<= 1) {
        for (unsigned int jj = kk >> 1; jj > 0; jj >>= 1) {
            if (t < 512) {
                unsigned int p = (unsigned int)t;
                unsigned int i = ((p & ~(jj - 1)) << 1) | (p & (jj - 1));
                unsigned int j = i | jj;
                unsigned long long a = SEL[i];
                unsigned long long c = SEL[j];
                bool desc = ((i & kk) == 0);
                if (desc ? (a < c) : (a > c)) { SEL[i] = c; SEL[j] = a; }
            }
            __syncthreads();
        }
    }

    for (unsigned int i = t; i < K_DIM; i += 1024)
        idx_out[b * K_DIM + i] =
            (int)(N_DIM - 1 - (unsigned int)(SEL[i] & 0xFFFFFFFFu));
}

// ---------------------------------------------------------------------------
// Gather: out[b, j, :] = x[b, idx[b*K + j], :].
// One float4 per thread; each 64-lane wave covers exactly one 1 KB row.
// ---------------------------------------------------------------------------
__global__ __launch_bounds__(256)
void gather_rows_kernel(const float* __restrict__ x,
                        const int* __restrict__ idx,
                        float* __restrict__ out) {
    size_t gid = (size_t)blockIdx.x * blockDim.x + threadIdx.x; // per float4
    int f4     = (int)(gid & (F_DIM / 4 - 1));   // 0..63
    size_t row = gid >> 6;                       // b*K + j
    int b      = (int)(row >> 10);               // / K_DIM
    int src    = idx[row];                       // wave-uniform -> broadcast

    const float4* src_ptr =
        (const float4*)(x + ((size_t)b * N_DIM + (size_t)src) * F_DIM) + f4;
    ((float4*)out)[gid] = *src_ptr;
}

extern "C" void kernel_launch(void* const* d_in, const int* in_sizes, int n_in,
                              void* d_out, int out_size, void* d_ws, size_t ws_size,
                              hipStream_t stream) {
    const float* x = (const float*)d_in[0];
    float* out = (float*)d_out;

    int* idx_ws = (int*)d_ws;   // 128 KB

    select_sort_kernel<<<B_DIM, 1024, 0, stream>>>(x, idx_ws);

    const size_t total_f4 = (size_t)B_DIM * K_DIM * F_DIM / 4;  // 2,097,152
    gather_rows_kernel<<<(int)(total_f4 / 256), 256, 0, stream>>>(x, idx_ws, out);
}